// Round 10
// baseline (213.850 us; speedup 1.0000x reference)
//
#include <hip/hip_runtime.h>
#include <math.h>

#define H 2048
#define V 50257
#define S 2048
#define LBLK 2048          // logits grid: 2048 blocks * 4 waves = 32 waves/CU

typedef float f32x4 __attribute__((ext_vector_type(4)));

__device__ inline float4 ntload4(const float* p) {
  f32x4 v = __builtin_nontemporal_load((const f32x4*)p);
  float4 r; r.x = v.x; r.y = v.y; r.z = v.z; r.w = v.w;
  return r;
}

__device__ inline float dot4(float4 a, float4 b) {
  return a.x * b.x + a.y * b.y + a.z * b.z + a.w * b.w;
}

__device__ inline float wave_sum(float v) {
#pragma unroll
  for (int o = 32; o > 0; o >>= 1) v += __shfl_down(v, o, 64);
  return v;
}

__device__ inline float wave_max(float v) {
#pragma unroll
  for (int o = 32; o > 0; o >>= 1) v = fmaxf(v, __shfl_down(v, o, 64));
  return v;
}

// One block per output unit i. Optionally zeroes zbuf for later atomics.
__global__ __launch_bounds__(256) void gru_kernel(
    const float* __restrict__ w_ih, const float* __restrict__ w_hh,
    const float* __restrict__ b_ih, const float* __restrict__ b_hh,
    const float* __restrict__ x_base, const int* __restrict__ word,
    const float* __restrict__ hprev,
    float* __restrict__ hout_ws, float* __restrict__ hout_d,
    float* __restrict__ zbuf, int zn) {
  const float* x = word ? (x_base + (size_t)word[0] * H) : x_base;
  const int i = blockIdx.x;
  const int t = threadIdx.x;
  const int zi = i * 256 + t;
  if (zbuf && zi < zn) zbuf[zi] = 0.f;
  const float4* x4 = (const float4*)x;
  const float4* h4 = (const float4*)hprev;
  float acc[6];
#pragma unroll
  for (int d = 0; d < 6; d++) acc[d] = 0.f;
#pragma unroll
  for (int g = 0; g < 3; g++) {
    const float* wi = w_ih + (size_t)(g * H + i) * H;
    const float* wh = w_hh + (size_t)(g * H + i) * H;
    float4 xa = x4[t], xb = x4[t + 256];
    float4 ha = h4[t], hb = h4[t + 256];
    acc[g]     = dot4(ntload4(wi + 4 * t), xa) +
                 dot4(ntload4(wi + 4 * (t + 256)), xb);
    acc[3 + g] = dot4(ntload4(wh + 4 * t), ha) +
                 dot4(ntload4(wh + 4 * (t + 256)), hb);
  }
  __shared__ float red[6][4];
  const int lane = t & 63, wid = t >> 6;
#pragma unroll
  for (int d = 0; d < 6; d++) {
    float s_ = wave_sum(acc[d]);
    if (lane == 0) red[d][wid] = s_;
  }
  __syncthreads();
  if (t == 0) {
    float gi_r = red[0][0] + red[0][1] + red[0][2] + red[0][3] + b_ih[i];
    float gi_z = red[1][0] + red[1][1] + red[1][2] + red[1][3] + b_ih[H + i];
    float gi_n = red[2][0] + red[2][1] + red[2][2] + red[2][3] + b_ih[2 * H + i];
    float gh_r = red[3][0] + red[3][1] + red[3][2] + red[3][3] + b_hh[i];
    float gh_z = red[4][0] + red[4][1] + red[4][2] + red[4][3] + b_hh[H + i];
    float gh_n = red[5][0] + red[5][1] + red[5][2] + red[5][3] + b_hh[2 * H + i];
    float r = 1.f / (1.f + expf(-(gi_r + gh_r)));
    float z = 1.f / (1.f + expf(-(gi_z + gh_z)));
    float n = tanhf(gi_n + r * gh_n);
    float h = (1.f - z) * n + z * hprev[i];
    hout_ws[i] = h;
    hout_d[i] = h;
  }
}

// dst[k] += sum_{j in tile jt} coef[j]*mat[j][k], via native f32 atomics.
// dst zeroed by the preceding kernel.  grid=(8, 32).
__global__ __launch_bounds__(256) void colsum_atomic_kernel(
    const float* __restrict__ mat, const float* __restrict__ coef,
    float* __restrict__ dst) {
  const int k = blockIdx.x * 256 + threadIdx.x;
  const int j0 = blockIdx.y * 64;
  float acc = 0.f;
#pragma unroll 4
  for (int j = j0; j < j0 + 64; j++)
    acc += coef[j] * __builtin_nontemporal_load(&mat[(size_t)j * H + k]);
  unsafeAtomicAdd(&dst[k], acc);
}

// e[row] = dot(enc[row], v). One wave per row, 4 rows/block. Blocks 0..7
// also zero ctx for the next kernel's atomics.
__global__ __launch_bounds__(256) void energies_kernel(
    const float* __restrict__ enc, const float* __restrict__ v,
    float* __restrict__ e, float* __restrict__ ctx) {
  const int wid = threadIdx.x >> 6, lane = threadIdx.x & 63;
  if (blockIdx.x < 8) ctx[blockIdx.x * 256 + threadIdx.x] = 0.f;
  const int row = blockIdx.x * 4 + wid;
  const float4* r4 = (const float4*)(enc + (size_t)row * H);
  const float4* v4 = (const float4*)v;
  float acc = 0.f;
#pragma unroll
  for (int k = 0; k < 8; k++) {
    int idx = lane + 64 * k;
    acc += dot4(r4[idx], v4[idx]);
  }
  acc = wave_sum(acc);
  if (lane == 0) e[row] = acc;
}

// Redundant per-block softmax stats, then atomic partial context colsum.
__global__ __launch_bounds__(256) void softmax_ctx_kernel(
    const float* __restrict__ enc, const float* __restrict__ e,
    float* __restrict__ ctx, float* __restrict__ attn_out) {
  const int t = threadIdx.x;
  const int kb = blockIdx.x;   // 0..7
  const int jt = blockIdx.y;   // 0..31
  const int lane = t & 63, wid = t >> 6;
  __shared__ float sred[4];
  __shared__ float wtile[64];
  float ev[8];
  float m = -INFINITY;
#pragma unroll
  for (int r = 0; r < 8; r++) {
    ev[r] = e[t + 256 * r];
    m = fmaxf(m, ev[r]);
  }
  float mw = wave_max(m);
  if (lane == 0) sred[wid] = mw;
  __syncthreads();
  const float M = fmaxf(fmaxf(sred[0], sred[1]), fmaxf(sred[2], sred[3]));
  float se = 0.f;
#pragma unroll
  for (int r = 0; r < 8; r++) se += expf(ev[r] - M);
  float sw = wave_sum(se);
  __syncthreads();
  if (lane == 0) sred[wid] = sw;
  __syncthreads();
  const float inv = 1.f / (sred[0] + sred[1] + sred[2] + sred[3]);
  const int j0 = jt * 64;
  if (t < 64) wtile[t] = expf(e[j0 + t] - M) * inv;
  __syncthreads();
  if (jt == 0) {
    const int s_idx = kb * 256 + t;
    attn_out[s_idx] = expf(e[s_idx] - M) * inv;
  }
  const int k = kb * 256 + t;
  float acc = 0.f;
#pragma unroll 4
  for (int j = 0; j < 64; j++)
    acc += wtile[j] * enc[(size_t)(j0 + j) * H + k];
  unsafeAtomicAdd(&ctx[k], acc);
}

// Grid-stride logits: 2048 blocks x 4 waves (max occupancy); each wave
// processes row-pairs (2 rows, 32 outstanding 16B loads/lane) with a
// running per-wave (max,sumexp); one pair per block at the end.
__global__ __launch_bounds__(256) void logits_kernel(
    const float* __restrict__ w_out, const float* __restrict__ b_out,
    const float* __restrict__ u, float* __restrict__ logits,
    float* __restrict__ pairs) {
  const int wid = threadIdx.x >> 6, lane = threadIdx.x & 63;
  const int gw = blockIdx.x * 4 + wid;      // global wave id, 0..8191
  const int npair = (V + 1) / 2;            // 25129
  const float4* u4 = (const float4*)u;
  float m_run = -INFINITY, s_run = 0.f;
  for (int p = gw; p < npair; p += LBLK * 4) {
    const int r0i = 2 * p;
    const bool has1 = (r0i + 1 < V);
    const float* p0 = w_out + (size_t)r0i * (2 * H);
    const float* p1 = w_out + (size_t)(has1 ? r0i + 1 : r0i) * (2 * H);
    float a0 = 0.f, a1 = 0.f;
#pragma unroll
    for (int k = 0; k < 16; k++) {
      int idx = lane + 64 * k;
      float4 uv = u4[idx];
      a0 += dot4(ntload4(p0 + 4 * idx), uv);
      a1 += dot4(ntload4(p1 + 4 * idx), uv);
    }
    a0 = wave_sum(a0);
    a1 = wave_sum(a1);
    if (lane == 0) {
      float l0 = a0 + b_out[r0i];
      logits[r0i] = l0;
      float Mn = fmaxf(m_run, l0);
      s_run = s_run * expf(m_run - Mn) + expf(l0 - Mn);
      m_run = Mn;
      if (has1) {
        float l1 = a1 + b_out[r0i + 1];
        logits[r0i + 1] = l1;
        Mn = fmaxf(m_run, l1);
        s_run = s_run * expf(m_run - Mn) + expf(l1 - Mn);
        m_run = Mn;
      }
    }
  }
  __shared__ float lm[4], ls[4];
  if (lane == 0) { lm[wid] = m_run; ls[wid] = s_run; }
  __syncthreads();
  if (threadIdx.x == 0) {
    float Mg = -INFINITY, Sg = 0.f;
#pragma unroll
    for (int i = 0; i < 4; i++) {
      float Mn = fmaxf(Mg, lm[i]);
      Sg = Sg * expf(Mg - Mn) + ls[i] * expf(lm[i] - Mn);
      Mg = Mn;
    }
    pairs[2 * blockIdx.x] = Mg;          // Sg==0 -> Mg=-inf, exp(-inf)=0 ok
    pairs[2 * blockIdx.x + 1] = Sg;
  }
}

// Each block redundantly combines all pairs (L2-hot, fixed order ->
// deterministic), then subtracts the constant from its slice of out.
__global__ __launch_bounds__(256) void lse_sub_kernel(
    const float* __restrict__ pairs, int npairs, float* __restrict__ out) {
  const int t = threadIdx.x;
  const int lane = t & 63, wid = t >> 6;
  __shared__ float sm[4], ss[4];
  __shared__ float cval;
  float M = -INFINITY, Ssum = 0.f;
  for (int i = t; i < npairs; i += 256) {
    float mb = pairs[2 * i], sb = pairs[2 * i + 1];
    float Mn = fmaxf(M, mb);
    Ssum = Ssum * expf(M - Mn) + sb * expf(mb - Mn);
    M = Mn;
  }
#pragma unroll
  for (int o = 32; o > 0; o >>= 1) {
    float mo = __shfl_down(M, o, 64);
    float so = __shfl_down(Ssum, o, 64);
    float Mn = fmaxf(M, mo);
    Ssum = Ssum * expf(M - Mn) + so * expf(mo - Mn);
    M = Mn;
  }
  if (lane == 0) { sm[wid] = M; ss[wid] = Ssum; }
  __syncthreads();
  if (t == 0) {
    float Mg = -INFINITY, Sg = 0.f;
#pragma unroll
    for (int i = 0; i < 4; i++) {
      float Mn = fmaxf(Mg, sm[i]);
      Sg = Sg * expf(Mg - Mn) + ss[i] * expf(sm[i] - Mn);
      Mg = Mn;
    }
    cval = Mg + logf(Sg);
  }
  __syncthreads();
  const float c = cval;
  const int i = blockIdx.x * 256 + t;
  if (i < V) out[i] -= c;
}

extern "C" void kernel_launch(void* const* d_in, const int* in_sizes, int n_in,
                              void* d_out, int out_size, void* d_ws, size_t ws_size,
                              hipStream_t stream) {
  const int*   word  = (const int*)d_in[0];
  const float* lasth = (const float*)d_in[1];
  const float* enc   = (const float*)d_in[2];
  const float* emb   = (const float*)d_in[3];
  const float* w_ih0 = (const float*)d_in[4];
  const float* w_hh0 = (const float*)d_in[5];
  const float* b_ih0 = (const float*)d_in[6];
  const float* b_hh0 = (const float*)d_in[7];
  const float* w_ih1 = (const float*)d_in[8];
  const float* w_hh1 = (const float*)d_in[9];
  const float* b_ih1 = (const float*)d_in[10];
  const float* b_hh1 = (const float*)d_in[11];
  const float* wa    = (const float*)d_in[12];
  // d_in[13] = ba: constant across s -> cancels in softmax.
  const float* w_out = (const float*)d_in[14];
  const float* b_out = (const float*)d_in[15];

  float* out      = (float*)d_out;
  float* h0_out   = out + V;
  float* h1_out   = out + V + H;
  float* attn_out = out + V + 2 * H;

  float* wsf   = (float*)d_ws;
  float* v     = wsf;                // H      (atomic acc, zeroed by gru1)
  float* e     = wsf + 2048;         // S
  float* u     = wsf + 4096;         // 2H: [h1 | context(atomic acc)]
  float* h0    = wsf + 8192;         // H
  float* pairs = wsf + 10240;        // 2*LBLK

  gru_kernel<<<H, 256, 0, stream>>>(w_ih0, w_hh0, b_ih0, b_hh0, emb, word,
                                    lasth, h0, h0_out, nullptr, 0);
  gru_kernel<<<H, 256, 0, stream>>>(w_ih1, w_hh1, b_ih1, b_hh1, h0, nullptr,
                                    lasth + H, u, h1_out, v, H);
  colsum_atomic_kernel<<<dim3(8, 32), 256, 0, stream>>>(wa, u, v);
  energies_kernel<<<S / 4, 256, 0, stream>>>(enc, v, e, u + H);
  softmax_ctx_kernel<<<dim3(8, 32), 256, 0, stream>>>(enc, e, u + H, attn_out);
  logits_kernel<<<LBLK, 256, 0, stream>>>(w_out, b_out, u, out, pairs);
  lse_sub_kernel<<<(V + 255) / 256, 256, 0, stream>>>(pairs, LBLK, out);
}

// Round 11
// 197.582 us; speedup vs baseline: 1.0823x; 1.0823x over previous
//
#include <hip/hip_runtime.h>
#include <math.h>

#define H 2048
#define V 50257
#define S 2048

typedef float f32x4 __attribute__((ext_vector_type(4)));

__device__ inline float4 ntload4(const float* p) {
  f32x4 v = __builtin_nontemporal_load((const f32x4*)p);
  float4 r; r.x = v.x; r.y = v.y; r.z = v.z; r.w = v.w;
  return r;
}

__device__ inline float dot4(float4 a, float4 b) {
  return a.x * b.x + a.y * b.y + a.z * b.z + a.w * b.w;
}

__device__ inline float wave_sum(float v) {
#pragma unroll
  for (int o = 32; o > 0; o >>= 1) v += __shfl_down(v, o, 64);
  return v;
}

__device__ inline float wave_max(float v) {
#pragma unroll
  for (int o = 32; o > 0; o >>= 1) v = fmaxf(v, __shfl_down(v, o, 64));
  return v;
}

// One block per output unit i. Optionally zeroes zbuf for later atomics.
__global__ __launch_bounds__(256) void gru_kernel(
    const float* __restrict__ w_ih, const float* __restrict__ w_hh,
    const float* __restrict__ b_ih, const float* __restrict__ b_hh,
    const float* __restrict__ x_base, const int* __restrict__ word,
    const float* __restrict__ hprev,
    float* __restrict__ hout_ws, float* __restrict__ hout_d,
    float* __restrict__ zbuf, int zn) {
  const float* x = word ? (x_base + (size_t)word[0] * H) : x_base;
  const int i = blockIdx.x;
  const int t = threadIdx.x;
  const int zi = i * 256 + t;
  if (zbuf && zi < zn) zbuf[zi] = 0.f;
  const float4* x4 = (const float4*)x;
  const float4* h4 = (const float4*)hprev;
  float acc[6];
#pragma unroll
  for (int d = 0; d < 6; d++) acc[d] = 0.f;
#pragma unroll
  for (int g = 0; g < 3; g++) {
    const float* wi = w_ih + (size_t)(g * H + i) * H;
    const float* wh = w_hh + (size_t)(g * H + i) * H;
    float4 xa = x4[t], xb = x4[t + 256];
    float4 ha = h4[t], hb = h4[t + 256];
    acc[g]     = dot4(ntload4(wi + 4 * t), xa) +
                 dot4(ntload4(wi + 4 * (t + 256)), xb);
    acc[3 + g] = dot4(ntload4(wh + 4 * t), ha) +
                 dot4(ntload4(wh + 4 * (t + 256)), hb);
  }
  __shared__ float red[6][4];
  const int lane = t & 63, wid = t >> 6;
#pragma unroll
  for (int d = 0; d < 6; d++) {
    float s_ = wave_sum(acc[d]);
    if (lane == 0) red[d][wid] = s_;
  }
  __syncthreads();
  if (t == 0) {
    float gi_r = red[0][0] + red[0][1] + red[0][2] + red[0][3] + b_ih[i];
    float gi_z = red[1][0] + red[1][1] + red[1][2] + red[1][3] + b_ih[H + i];
    float gi_n = red[2][0] + red[2][1] + red[2][2] + red[2][3] + b_ih[2 * H + i];
    float gh_r = red[3][0] + red[3][1] + red[3][2] + red[3][3] + b_hh[i];
    float gh_z = red[4][0] + red[4][1] + red[4][2] + red[4][3] + b_hh[H + i];
    float gh_n = red[5][0] + red[5][1] + red[5][2] + red[5][3] + b_hh[2 * H + i];
    float r = 1.f / (1.f + expf(-(gi_r + gh_r)));
    float z = 1.f / (1.f + expf(-(gi_z + gh_z)));
    float n = tanhf(gi_n + r * gh_n);
    float h = (1.f - z) * n + z * hprev[i];
    hout_ws[i] = h;
    hout_d[i] = h;
  }
}

// dst[k] += sum_{j in tile jt} coef[j]*mat[j][k], via native f32 atomics.
// dst zeroed by the preceding kernel.  grid=(8, 32).
__global__ __launch_bounds__(256) void colsum_atomic_kernel(
    const float* __restrict__ mat, const float* __restrict__ coef,
    float* __restrict__ dst) {
  const int k = blockIdx.x * 256 + threadIdx.x;
  const int j0 = blockIdx.y * 64;
  float acc = 0.f;
#pragma unroll 4
  for (int j = j0; j < j0 + 64; j++)
    acc += coef[j] * __builtin_nontemporal_load(&mat[(size_t)j * H + k]);
  unsafeAtomicAdd(&dst[k], acc);
}

// e[row] = dot(enc[row], v). One wave per row, 4 rows/block. Blocks 0..7
// also zero ctx for the next kernel's atomics.
__global__ __launch_bounds__(256) void energies_kernel(
    const float* __restrict__ enc, const float* __restrict__ v,
    float* __restrict__ e, float* __restrict__ ctx) {
  const int wid = threadIdx.x >> 6, lane = threadIdx.x & 63;
  if (blockIdx.x < 8) ctx[blockIdx.x * 256 + threadIdx.x] = 0.f;
  const int row = blockIdx.x * 4 + wid;
  const float4* r4 = (const float4*)(enc + (size_t)row * H);
  const float4* v4 = (const float4*)v;
  float acc = 0.f;
#pragma unroll
  for (int k = 0; k < 8; k++) {
    int idx = lane + 64 * k;
    acc += dot4(r4[idx], v4[idx]);
  }
  acc = wave_sum(acc);
  if (lane == 0) e[row] = acc;
}

// Redundant per-block softmax stats, then atomic partial context colsum.
__global__ __launch_bounds__(256) void softmax_ctx_kernel(
    const float* __restrict__ enc, const float* __restrict__ e,
    float* __restrict__ ctx, float* __restrict__ attn_out) {
  const int t = threadIdx.x;
  const int kb = blockIdx.x;   // 0..7
  const int jt = blockIdx.y;   // 0..31
  const int lane = t & 63, wid = t >> 6;
  __shared__ float sred[4];
  __shared__ float wtile[64];
  float ev[8];
  float m = -INFINITY;
#pragma unroll
  for (int r = 0; r < 8; r++) {
    ev[r] = e[t + 256 * r];
    m = fmaxf(m, ev[r]);
  }
  float mw = wave_max(m);
  if (lane == 0) sred[wid] = mw;
  __syncthreads();
  const float M = fmaxf(fmaxf(sred[0], sred[1]), fmaxf(sred[2], sred[3]));
  float se = 0.f;
#pragma unroll
  for (int r = 0; r < 8; r++) se += expf(ev[r] - M);
  float sw = wave_sum(se);
  __syncthreads();
  if (lane == 0) sred[wid] = sw;
  __syncthreads();
  const float inv = 1.f / (sred[0] + sred[1] + sred[2] + sred[3]);
  const int j0 = jt * 64;
  if (t < 64) wtile[t] = expf(e[j0 + t] - M) * inv;
  __syncthreads();
  if (jt == 0) {
    const int s_idx = kb * 256 + t;
    attn_out[s_idx] = expf(e[s_idx] - M) * inv;
  }
  const int k = kb * 256 + t;
  float acc = 0.f;
#pragma unroll 4
  for (int j = 0; j < 64; j++)
    acc += wtile[j] * enc[(size_t)(j0 + j) * H + k];
  unsafeAtomicAdd(&ctx[k], acc);
}

// 8 rows/block, 2 rows/wave: logits + per-block (max, sumexp) pair.
__global__ __launch_bounds__(256) void logits_kernel(
    const float* __restrict__ w_out, const float* __restrict__ b_out,
    const float* __restrict__ u, float* __restrict__ logits,
    float* __restrict__ pairs) {
  const int wid = threadIdx.x >> 6, lane = threadIdx.x & 63;
  const int base = blockIdx.x * 8 + wid * 2;
  __shared__ float lvals[8];
  float l0 = -INFINITY, l1 = -INFINITY;
  if (base < V) {
    const bool has1 = (base + 1 < V);
    const float* r0 = w_out + (size_t)base * (2 * H);
    const float* r1 = w_out + (size_t)(has1 ? base + 1 : base) * (2 * H);
    const float4* u4 = (const float4*)u;
    float acc0 = 0.f, acc1 = 0.f;
#pragma unroll
    for (int k = 0; k < 16; k++) {
      int idx = lane + 64 * k;
      float4 uv = u4[idx];
      acc0 += dot4(ntload4(r0 + 4 * idx), uv);
      acc1 += dot4(ntload4(r1 + 4 * idx), uv);
    }
    acc0 = wave_sum(acc0);
    acc1 = wave_sum(acc1);
    if (lane == 0) {
      l0 = acc0 + b_out[base];
      logits[base] = l0;
      if (has1) {
        l1 = acc1 + b_out[base + 1];
        logits[base + 1] = l1;
      }
    }
  }
  if (lane == 0) { lvals[wid * 2] = l0; lvals[wid * 2 + 1] = l1; }
  __syncthreads();
  if (threadIdx.x == 0) {
    float M = -INFINITY;
#pragma unroll
    for (int i = 0; i < 8; i++) M = fmaxf(M, lvals[i]);
    float se = 0.f;
#pragma unroll
    for (int i = 0; i < 8; i++) se += expf(lvals[i] - M);  // exp(-inf)=0
    pairs[2 * blockIdx.x] = M;
    pairs[2 * blockIdx.x + 1] = se;
  }
}

// Each block redundantly combines all pairs (L2-hot, fixed order ->
// deterministic), then subtracts the constant from its slice of out.
__global__ __launch_bounds__(256) void lse_sub_kernel(
    const float* __restrict__ pairs, int npairs, float* __restrict__ out) {
  const int t = threadIdx.x;
  const int lane = t & 63, wid = t >> 6;
  __shared__ float sm[4], ss[4];
  __shared__ float cval;
  float M = -INFINITY, Ssum = 0.f;
  for (int i = t; i < npairs; i += 256) {
    float mb = pairs[2 * i], sb = pairs[2 * i + 1];
    float Mn = fmaxf(M, mb);
    Ssum = Ssum * expf(M - Mn) + sb * expf(mb - Mn);
    M = Mn;
  }
#pragma unroll
  for (int o = 32; o > 0; o >>= 1) {
    float mo = __shfl_down(M, o, 64);
    float so = __shfl_down(Ssum, o, 64);
    float Mn = fmaxf(M, mo);
    Ssum = Ssum * expf(M - Mn) + so * expf(mo - Mn);
    M = Mn;
  }
  if (lane == 0) { sm[wid] = M; ss[wid] = Ssum; }
  __syncthreads();
  if (t == 0) {
    float Mg = -INFINITY, Sg = 0.f;
#pragma unroll
    for (int i = 0; i < 4; i++) {
      float Mn = fmaxf(Mg, sm[i]);
      Sg = Sg * expf(Mg - Mn) + ss[i] * expf(sm[i] - Mn);
      Mg = Mn;
    }
    cval = Mg + logf(Sg);
  }
  __syncthreads();
  const float c = cval;
  const int i = blockIdx.x * 256 + t;
  if (i < V) out[i] -= c;
}

extern "C" void kernel_launch(void* const* d_in, const int* in_sizes, int n_in,
                              void* d_out, int out_size, void* d_ws, size_t ws_size,
                              hipStream_t stream) {
  const int*   word  = (const int*)d_in[0];
  const float* lasth = (const float*)d_in[1];
  const float* enc   = (const float*)d_in[2];
  const float* emb   = (const float*)d_in[3];
  const float* w_ih0 = (const float*)d_in[4];
  const float* w_hh0 = (const float*)d_in[5];
  const float* b_ih0 = (const float*)d_in[6];
  const float* b_hh0 = (const float*)d_in[7];
  const float* w_ih1 = (const float*)d_in[8];
  const float* w_hh1 = (const float*)d_in[9];
  const float* b_ih1 = (const float*)d_in[10];
  const float* b_hh1 = (const float*)d_in[11];
  const float* wa    = (const float*)d_in[12];
  // d_in[13] = ba: constant across s -> cancels in softmax.
  const float* w_out = (const float*)d_in[14];
  const float* b_out = (const float*)d_in[15];

  float* out      = (float*)d_out;
  float* h0_out   = out + V;
  float* h1_out   = out + V + H;
  float* attn_out = out + V + 2 * H;

  float* wsf   = (float*)d_ws;
  float* v     = wsf;                // H      (atomic acc, zeroed by gru1)
  float* e     = wsf + 2048;         // S
  float* u     = wsf + 4096;         // 2H: [h1 | context(atomic acc)]
  float* h0    = wsf + 8192;         // H
  float* pairs = wsf + 10240;        // 2*6283

  const int nblk = (V + 7) / 8;      // 6283

  gru_kernel<<<H, 256, 0, stream>>>(w_ih0, w_hh0, b_ih0, b_hh0, emb, word,
                                    lasth, h0, h0_out, nullptr, 0);
  gru_kernel<<<H, 256, 0, stream>>>(w_ih1, w_hh1, b_ih1, b_hh1, h0, nullptr,
                                    lasth + H, u, h1_out, v, H);
  colsum_atomic_kernel<<<dim3(8, 32), 256, 0, stream>>>(wa, u, v);
  energies_kernel<<<S / 4, 256, 0, stream>>>(enc, v, e, u + H);
  softmax_ctx_kernel<<<dim3(8, 32), 256, 0, stream>>>(enc, e, u + H, attn_out);
  logits_kernel<<<nblk, 256, 0, stream>>>(w_out, b_out, u, out, pairs);
  lse_sub_kernel<<<(V + 255) / 256, 256, 0, stream>>>(pairs, nblk, out);
}